// Round 9
// baseline (801.907 us; speedup 1.0000x reference)
//
#include <hip/hip_runtime.h>
#include <cstdint>

typedef __bf16 bf16;
typedef __bf16 bf16x8 __attribute__((ext_vector_type(8)));
typedef float f32x4 __attribute__((ext_vector_type(4)));

// Split 8 fp32 into hi/lo bf16 planes (hi = round(v), lo = round(v - hi)).
__device__ __forceinline__ void split8v(const float4& a, const float4& b, bf16x8& h, bf16x8& l)
{
    float v[8] = {a.x, a.y, a.z, a.w, b.x, b.y, b.z, b.w};
#pragma unroll
    for (int j = 0; j < 8; ++j) {
        bf16 hh = (bf16)v[j];
        h[j] = hh;
        l[j] = (bf16)(v[j] - (float)hh);
    }
}

// ---------------------------------------------------------------------------
// LN1 -> xres (fp32, x rows only) and LN_att(LN1) -> h (fp32, all 6272 rows).
// ---------------------------------------------------------------------------
__global__ __launch_bounds__(256) void prep_ln(
    const float* __restrict__ x, const float* __restrict__ memory,
    const float* __restrict__ g1, const float* __restrict__ b1,
    const float* __restrict__ ga, const float* __restrict__ ba,
    float* __restrict__ xres, float* __restrict__ h)
{
    const int row = blockIdx.x;            // 0..6271
    const int b = row / 1568, l = row - b * 1568;
    const float* src = (l < 784) ? (memory + ((size_t)b * 1024 + l) * 768)
                                 : (x + ((size_t)b * 784 + (l - 784)) * 768);
    const int t = threadIdx.x, lane = t & 63, wv = t >> 6;
    __shared__ float red[8];

    float v[3];
#pragma unroll
    for (int i = 0; i < 3; ++i) v[i] = src[i * 256 + t];

    float s = v[0] + v[1] + v[2];
    float s2 = v[0] * v[0] + v[1] * v[1] + v[2] * v[2];
#pragma unroll
    for (int off = 1; off < 64; off <<= 1) { s += __shfl_xor(s, off, 64); s2 += __shfl_xor(s2, off, 64); }
    if (lane == 0) { red[wv] = s; red[4 + wv] = s2; }
    __syncthreads();
    s = red[0] + red[1] + red[2] + red[3];
    s2 = red[4] + red[5] + red[6] + red[7];
    float mu = s * (1.0f / 768.0f);
    float var = s2 * (1.0f / 768.0f) - mu * mu;
    float rs = rsqrtf(fmaxf(var, 0.0f) + 1e-5f);

    float w[3];
#pragma unroll
    for (int i = 0; i < 3; ++i) {
        int c = i * 256 + t;
        w[i] = (v[i] - mu) * rs * g1[c] + b1[c];
    }
    if (l >= 784) {
        float* xr = xres + ((size_t)b * 784 + (l - 784)) * 768;
#pragma unroll
        for (int i = 0; i < 3; ++i) xr[i * 256 + t] = w[i];
    }

    s = w[0] + w[1] + w[2];
    s2 = w[0] * w[0] + w[1] * w[1] + w[2] * w[2];
#pragma unroll
    for (int off = 1; off < 64; off <<= 1) { s += __shfl_xor(s, off, 64); s2 += __shfl_xor(s2, off, 64); }
    __syncthreads();
    if (lane == 0) { red[wv] = s; red[4 + wv] = s2; }
    __syncthreads();
    s = red[0] + red[1] + red[2] + red[3];
    s2 = red[4] + red[5] + red[6] + red[7];
    float mu2 = s * (1.0f / 768.0f);
    float var2 = s2 * (1.0f / 768.0f) - mu2 * mu2;
    float rs2 = rsqrtf(fmaxf(var2, 0.0f) + 1e-5f);

    float* hr = h + (size_t)row * 768;
#pragma unroll
    for (int i = 0; i < 3; ++i) {
        int c = i * 256 + t;
        hr[c] = (w[i] - mu2) * rs2 * ga[c] + ba[c];
    }
}

// ---------------------------------------------------------------------------
// Split-bf16 GEMM: C[M,N] = A[M,K]*B[N,K]^T, fp32-grade accuracy.
// 128x128 tile, BK=32, 4 waves x 64x64, 16x16x32 MFMA (3 per hi/lo product).
// MODE 0: fp32. 1: fp32 acc+bias. 2: fp32 silu(acc+bias). 3: fp32 acc+bias+resid.
// ---------------------------------------------------------------------------
template <int MODE>
__global__ __launch_bounds__(256, 2) void gemm_bt(
    const float* __restrict__ A, const float* __restrict__ Bm,
    int M, int N, int K,
    const float* __restrict__ bias, const float* __restrict__ resid,
    float* __restrict__ Cv)
{
    __shared__ __align__(16) bf16 Ah[128 * 32], Al[128 * 32];
    __shared__ __align__(16) bf16 Bh[128 * 32], Bl[128 * 32];
    const int t = threadIdx.x, lane = t & 63, wv = t >> 6;
    const int row0 = blockIdx.y * 128, col0 = blockIdx.x * 128;
    const int ro = (wv >> 1) * 64, co = (wv & 1) * 64;

    f32x4 acc[4][4] = {};

    for (int k0 = 0; k0 < K; k0 += 32) {
#pragma unroll
        for (int it = 0; it < 2; ++it) {
            int f = it * 256 + t;
            int r = f >> 2, kc = (f & 3) * 8;
            int ra = row0 + r; if (ra >= M) ra = M - 1;
            const float* ap = A + (size_t)ra * K + k0 + kc;
            const float* bp = Bm + (size_t)(col0 + r) * K + k0 + kc;
            float4 a0 = *(const float4*)ap, a1 = *(const float4*)(ap + 4);
            float4 b0 = *(const float4*)bp, b1 = *(const float4*)(bp + 4);
            bf16x8 h8, l8;
            split8v(a0, a1, h8, l8);
            *(bf16x8*)&Ah[f * 8] = h8; *(bf16x8*)&Al[f * 8] = l8;
            split8v(b0, b1, h8, l8);
            *(bf16x8*)&Bh[f * 8] = h8; *(bf16x8*)&Bl[f * 8] = l8;
        }
        __syncthreads();
        bf16x8 ah[4], al[4], bh[4], bl[4];
#pragma unroll
        for (int i = 0; i < 4; ++i) {
            int o = (ro + i * 16 + (lane & 15)) * 32 + (lane >> 4) * 8;
            ah[i] = *(const bf16x8*)&Ah[o];
            al[i] = *(const bf16x8*)&Al[o];
        }
#pragma unroll
        for (int j = 0; j < 4; ++j) {
            int o = (co + j * 16 + (lane & 15)) * 32 + (lane >> 4) * 8;
            bh[j] = *(const bf16x8*)&Bh[o];
            bl[j] = *(const bf16x8*)&Bl[o];
        }
#pragma unroll
        for (int i = 0; i < 4; ++i)
#pragma unroll
            for (int j = 0; j < 4; ++j) {
                acc[i][j] = __builtin_amdgcn_mfma_f32_16x16x32_bf16(al[i], bh[j], acc[i][j], 0, 0, 0);
                acc[i][j] = __builtin_amdgcn_mfma_f32_16x16x32_bf16(ah[i], bl[j], acc[i][j], 0, 0, 0);
                acc[i][j] = __builtin_amdgcn_mfma_f32_16x16x32_bf16(ah[i], bh[j], acc[i][j], 0, 0, 0);
            }
        __syncthreads();
    }

#pragma unroll
    for (int i = 0; i < 4; ++i)
#pragma unroll
        for (int j = 0; j < 4; ++j)
#pragma unroll
            for (int r = 0; r < 4; ++r) {
                int row = row0 + ro + i * 16 + (lane >> 4) * 4 + r;
                int col = col0 + co + j * 16 + (lane & 15);
                if (row >= M) continue;
                float v = acc[i][j][r];
                size_t idx = (size_t)row * N + col;
                if (MODE == 0) {
                    Cv[idx] = v;
                } else if (MODE == 1) {
                    Cv[idx] = v + bias[col];
                } else if (MODE == 2) {
                    v += bias[col];
                    Cv[idx] = v / (1.0f + __expf(-v));
                } else {
                    Cv[idx] = v + bias[col] + resid[idx];   // fp32 OUTPUT (root-cause fix)
                }
            }
}

// ---------------------------------------------------------------------------
// Flash-style attention, split-bf16 precision, analytic MAC mask
// (query window w attends keys [0,(5+w)*196) — proven == real mask, R4≡R5).
// Block per (w, h, b). qkv fp32 [b,1568,2304]; out fp32.
// ---------------------------------------------------------------------------
__global__ __launch_bounds__(256) void attn_kernel(
    const float* __restrict__ qkv, float* __restrict__ out)
{
    const int w = blockIdx.x, hh = blockIdx.y, b = blockIdx.z;
    const int kmax = (5 + w) * 196;
    const int nkt = (kmax + 31) / 32;
    const int t = threadIdx.x, lane = t & 63, wv = t >> 6;

    __shared__ __align__(16) bf16 Ks_h[32][64], Ks_l[32][64];
    __shared__ __align__(16) bf16 Vt_h[64][32], Vt_l[64][32];
    __shared__ __align__(16) bf16 Pl_h[4][16][32], Pl_l[4][16][32];

    const size_t bbase = (size_t)b * 1568 * 2304;

    bf16x8 qh[4][2], ql[4][2];
    float m_i[4][4], l_i[4][4];
    f32x4 oacc[4][4];
#pragma unroll
    for (int ti = 0; ti < 4; ++ti) {
        int tile = ti * 4 + wv; if (tile > 12) tile = 12;
        int qr = tile * 16 + (lane & 15); if (qr > 195) qr = 195;
        const float* qp = qkv + bbase + (size_t)(784 + w * 196 + qr) * 2304 + hh * 64 + (lane >> 4) * 8;
#pragma unroll
        for (int p = 0; p < 2; ++p) {
            float4 a0 = *(const float4*)(qp + p * 32);
            float4 a1 = *(const float4*)(qp + p * 32 + 4);
            a0.x *= 0.125f; a0.y *= 0.125f; a0.z *= 0.125f; a0.w *= 0.125f;
            a1.x *= 0.125f; a1.y *= 0.125f; a1.z *= 0.125f; a1.w *= 0.125f;
            split8v(a0, a1, qh[ti][p], ql[ti][p]);
        }
#pragma unroll
        for (int r = 0; r < 4; ++r) { m_i[ti][r] = -1e30f; l_i[ti][r] = 0.0f; }
#pragma unroll
        for (int nd = 0; nd < 4; ++nd) oacc[ti][nd] = f32x4{0.f, 0.f, 0.f, 0.f};
    }

    for (int kt = 0; kt < nkt; ++kt) {
        __syncthreads();
        {
            int row = t >> 3, c8 = (t & 7) * 8;
            const float* kp = qkv + bbase + (size_t)(kt * 32 + row) * 2304 + 768 + hh * 64 + c8;
            float4 k0 = *(const float4*)kp, k1 = *(const float4*)(kp + 4);
            bf16x8 h8, l8;
            split8v(k0, k1, h8, l8);
            *(bf16x8*)&Ks_h[row][c8] = h8;
            *(bf16x8*)&Ks_l[row][c8] = l8;
            float4 v0 = *(const float4*)(kp + 768), v1 = *(const float4*)(kp + 772);
            float vv[8] = {v0.x, v0.y, v0.z, v0.w, v1.x, v1.y, v1.z, v1.w};
#pragma unroll
            for (int j = 0; j < 8; ++j) {
                bf16 vh = (bf16)vv[j];
                Vt_h[c8 + j][row] = vh;
                Vt_l[c8 + j][row] = (bf16)(vv[j] - (float)vh);
            }
        }
        __syncthreads();

        bf16x8 kfh[2][2], kfl[2][2], vth[4], vtl[4];
#pragma unroll
        for (int nb = 0; nb < 2; ++nb)
#pragma unroll
            for (int p = 0; p < 2; ++p) {
                kfh[nb][p] = *(const bf16x8*)&Ks_h[nb * 16 + (lane & 15)][p * 32 + (lane >> 4) * 8];
                kfl[nb][p] = *(const bf16x8*)&Ks_l[nb * 16 + (lane & 15)][p * 32 + (lane >> 4) * 8];
            }
#pragma unroll
        for (int nd = 0; nd < 4; ++nd) {
            vth[nd] = *(const bf16x8*)&Vt_h[nd * 16 + (lane & 15)][(lane >> 4) * 8];
            vtl[nd] = *(const bf16x8*)&Vt_l[nd * 16 + (lane & 15)][(lane >> 4) * 8];
        }

#pragma unroll
        for (int ti = 0; ti < 4; ++ti) {
            int tile = ti * 4 + wv;
            if (tile > 12) continue;              // wave-uniform
            f32x4 s0 = {0.f, 0.f, 0.f, 0.f}, s1 = {0.f, 0.f, 0.f, 0.f};
#pragma unroll
            for (int p = 0; p < 2; ++p) {
                s0 = __builtin_amdgcn_mfma_f32_16x16x32_bf16(ql[ti][p], kfh[0][p], s0, 0, 0, 0);
                s0 = __builtin_amdgcn_mfma_f32_16x16x32_bf16(qh[ti][p], kfl[0][p], s0, 0, 0, 0);
                s0 = __builtin_amdgcn_mfma_f32_16x16x32_bf16(qh[ti][p], kfh[0][p], s0, 0, 0, 0);
                s1 = __builtin_amdgcn_mfma_f32_16x16x32_bf16(ql[ti][p], kfh[1][p], s1, 0, 0, 0);
                s1 = __builtin_amdgcn_mfma_f32_16x16x32_bf16(qh[ti][p], kfl[1][p], s1, 0, 0, 0);
                s1 = __builtin_amdgcn_mfma_f32_16x16x32_bf16(qh[ti][p], kfh[1][p], s1, 0, 0, 0);
            }
            const float NEG = -1e30f;
            int key0 = kt * 32 + (lane & 15);
            if (key0 >= kmax)      { s0[0] = s0[1] = s0[2] = s0[3] = NEG; }
            if (key0 + 16 >= kmax) { s1[0] = s1[1] = s1[2] = s1[3] = NEG; }
#pragma unroll
            for (int r = 0; r < 4; ++r) {
                float mx = fmaxf(s0[r], s1[r]);
#pragma unroll
                for (int off = 1; off < 16; off <<= 1) mx = fmaxf(mx, __shfl_xor(mx, off, 64));
                float mnew = fmaxf(m_i[ti][r], mx);
                float alpha = __expf(m_i[ti][r] - mnew);
                float p0 = (s0[r] < -1e29f) ? 0.0f : __expf(s0[r] - mnew);
                float p1 = (s1[r] < -1e29f) ? 0.0f : __expf(s1[r] - mnew);
                float sum = p0 + p1;
#pragma unroll
                for (int off = 1; off < 16; off <<= 1) sum += __shfl_xor(sum, off, 64);
                l_i[ti][r] = l_i[ti][r] * alpha + sum;
                m_i[ti][r] = mnew;
#pragma unroll
                for (int nd = 0; nd < 4; ++nd) oacc[ti][nd][r] *= alpha;
                int pr = (lane >> 4) * 4 + r, pc = lane & 15;
                bf16 p0h = (bf16)p0, p1h = (bf16)p1;
                Pl_h[wv][pr][pc] = p0h;       Pl_l[wv][pr][pc] = (bf16)(p0 - (float)p0h);
                Pl_h[wv][pr][16 + pc] = p1h;  Pl_l[wv][pr][16 + pc] = (bf16)(p1 - (float)p1h);
            }
            asm volatile("s_waitcnt lgkmcnt(0)" ::: "memory");  // wave-private Pl RAW
            bf16x8 pfh = *(const bf16x8*)&Pl_h[wv][lane & 15][(lane >> 4) * 8];
            bf16x8 pfl = *(const bf16x8*)&Pl_l[wv][lane & 15][(lane >> 4) * 8];
#pragma unroll
            for (int nd = 0; nd < 4; ++nd) {
                oacc[ti][nd] = __builtin_amdgcn_mfma_f32_16x16x32_bf16(pfl, vth[nd], oacc[ti][nd], 0, 0, 0);
                oacc[ti][nd] = __builtin_amdgcn_mfma_f32_16x16x32_bf16(pfh, vtl[nd], oacc[ti][nd], 0, 0, 0);
                oacc[ti][nd] = __builtin_amdgcn_mfma_f32_16x16x32_bf16(pfh, vth[nd], oacc[ti][nd], 0, 0, 0);
            }
        }
    }

#pragma unroll
    for (int ti = 0; ti < 4; ++ti) {
        int tile = ti * 4 + wv;
        if (tile > 12) continue;
#pragma unroll
        for (int r = 0; r < 4; ++r) {
            int qr = tile * 16 + (lane >> 4) * 4 + r;
            if (qr >= 196) continue;
            float inv = 1.0f / l_i[ti][r];
            size_t row = (size_t)b * 784 + w * 196 + qr;
#pragma unroll
            for (int nd = 0; nd < 4; ++nd)
                out[row * 768 + hh * 64 + nd * 16 + (lane & 15)] = oacc[ti][nd][r] * inv;
        }
    }
}

// ---------------------------------------------------------------------------
// y = xres + att (fp32), y2 = LN2(y) (fp32). Block per x-row (3136).
// ---------------------------------------------------------------------------
__global__ __launch_bounds__(256) void ln2_resid(
    const float* __restrict__ xres, const float* __restrict__ att,
    const float* __restrict__ g2, const float* __restrict__ b2,
    float* __restrict__ y, float* __restrict__ y2)
{
    const int row = blockIdx.x;
    const float* xr = xres + (size_t)row * 768;
    const float* ar = att + (size_t)row * 768;
    const int t = threadIdx.x, lane = t & 63, wv = t >> 6;
    __shared__ float red[8];

    float v[3];
    float* yr = y + (size_t)row * 768;
#pragma unroll
    for (int i = 0; i < 3; ++i) {
        int c = i * 256 + t;
        v[i] = xr[c] + ar[c];
        yr[c] = v[i];
    }
    float s = v[0] + v[1] + v[2];
    float s2 = v[0] * v[0] + v[1] * v[1] + v[2] * v[2];
#pragma unroll
    for (int off = 1; off < 64; off <<= 1) { s += __shfl_xor(s, off, 64); s2 += __shfl_xor(s2, off, 64); }
    if (lane == 0) { red[wv] = s; red[4 + wv] = s2; }
    __syncthreads();
    s = red[0] + red[1] + red[2] + red[3];
    s2 = red[4] + red[5] + red[6] + red[7];
    float mu = s * (1.0f / 768.0f);
    float var = s2 * (1.0f / 768.0f) - mu * mu;
    float rs = rsqrtf(fmaxf(var, 0.0f) + 1e-5f);

    float* y2r = y2 + (size_t)row * 768;
#pragma unroll
    for (int i = 0; i < 3; ++i) {
        int c = i * 256 + t;
        y2r[c] = (v[i] - mu) * rs * g2[c] + b2[c];
    }
}

// ---------------------------------------------------------------------------
extern "C" void kernel_launch(void* const* d_in, const int* in_sizes, int n_in,
                              void* d_out, int out_size, void* d_ws, size_t ws_size,
                              hipStream_t stream)
{
    (void)in_sizes; (void)n_in; (void)out_size; (void)ws_size;
    const float* x        = (const float*)d_in[0];
    const float* memory   = (const float*)d_in[1];
    const float* ln_att_g = (const float*)d_in[2];
    const float* ln_att_b = (const float*)d_in[3];
    const float* w_qkv    = (const float*)d_in[4];
    const float* w_out    = (const float*)d_in[5];
    const float* b_out    = (const float*)d_in[6];
    const float* ln1_g    = (const float*)d_in[7];
    const float* ln1_b    = (const float*)d_in[8];
    const float* ln2_g    = (const float*)d_in[9];
    const float* ln2_b    = (const float*)d_in[10];
    const float* w1       = (const float*)d_in[11];
    const float* b1       = (const float*)d_in[12];
    const float* w2       = (const float*)d_in[13];
    const float* b2       = (const float*)d_in[14];

    // ---- workspace: units of SZ_R = 3136*768*4 B; total 10*SZ_R ≈ 96.3 MB ----
    char* ws = (char*)d_ws;
    const size_t SZ_R = (size_t)3136 * 768 * 4;
    float* xres    = (float*)(ws);                 // [0,1)   fp32 3136x768
    float* hbuf    = (float*)(ws + SZ_R);          // [1,3)   fp32 6272x768
    float* att_f32 = (float*)(ws + SZ_R);          // [1,2)   reuse hbuf after QKV GEMM
    float* y       = (float*)(ws + 2 * SZ_R);      // [2,3)   hbuf tail, dead after QKV
    float* qkv     = (float*)(ws + 3 * SZ_R);      // [3,9)   fp32 6272x2304
    float* ffbuf   = (float*)(ws + 3 * SZ_R);      // [3,7)   reuse qkv after attention
    float* attnout = (float*)(ws + 9 * SZ_R);      // [9,10)  fp32 3136x768
    float* y2      = (float*)(ws + 9 * SZ_R);      // [9,10)  reuse attnout after out-proj

    // 1) LN1 + LN_att
    prep_ln<<<6272, 256, 0, stream>>>(x, memory, ln1_g, ln1_b, ln_att_g, ln_att_b, xres, hbuf);

    // 2) qkv = h @ w_qkv^T   (M=6272, N=2304, K=768)
    gemm_bt<0><<<dim3(18, 49), 256, 0, stream>>>(hbuf, w_qkv, 6272, 2304, 768, nullptr, nullptr, qkv);

    // 3) attention (windowed, block-causal)
    attn_kernel<<<dim3(4, 12, 4), 256, 0, stream>>>(qkv, attnout);

    // 4) att = attnout @ w_out^T + b_out  (M=3136, N=768, K=768)
    gemm_bt<1><<<dim3(6, 25), 256, 0, stream>>>(attnout, w_out, 3136, 768, 768, b_out, nullptr, att_f32);

    // 5) y = xres + att ; y2 = LN2(y)
    ln2_resid<<<3136, 256, 0, stream>>>(xres, att_f32, ln2_g, ln2_b, y, y2);

    // 6) ff = silu(y2 @ w1^T + b1)   (M=3136, N=3072, K=768)
    gemm_bt<2><<<dim3(24, 25), 256, 0, stream>>>(y2, w1, 3136, 3072, 768, b1, nullptr, ffbuf);

    // 7) out = y + ff @ w2^T + b2    (M=3136, N=768, K=3072)  -> fp32 d_out
    gemm_bt<3><<<dim3(6, 25), 256, 0, stream>>>(ffbuf, w2, 3136, 768, 3072, b2, y, (float*)d_out);
}

// Round 10
// 668.366 us; speedup vs baseline: 1.1998x; 1.1998x over previous
//
#include <hip/hip_runtime.h>
#include <cstdint>

typedef __bf16 bf16;
typedef __bf16 bf16x8 __attribute__((ext_vector_type(8)));
typedef float f32x4 __attribute__((ext_vector_type(4)));

// ---------------------------------------------------------------------------
// fp32 -> (hi, lo) bf16 planes. hi = round(v), lo = round(v - hi).
// ---------------------------------------------------------------------------
__global__ __launch_bounds__(256) void split_planes(const float* __restrict__ src,
                                                    bf16* __restrict__ h,
                                                    bf16* __restrict__ l, int n)
{
    const int stride = gridDim.x * blockDim.x;
    for (int i = blockIdx.x * blockDim.x + threadIdx.x; i < n; i += stride) {
        float v = src[i];
        bf16 hh = (bf16)v;
        h[i] = hh;
        l[i] = (bf16)(v - (float)hh);
    }
}

// ---------------------------------------------------------------------------
// LN1 -> xres (fp32, x rows only); LN_att(LN1) -> h hi/lo planes (all rows).
// ---------------------------------------------------------------------------
__global__ __launch_bounds__(256) void prep_ln(
    const float* __restrict__ x, const float* __restrict__ memory,
    const float* __restrict__ g1, const float* __restrict__ b1,
    const float* __restrict__ ga, const float* __restrict__ ba,
    float* __restrict__ xres, bf16* __restrict__ hH, bf16* __restrict__ hL)
{
    const int row = blockIdx.x;            // 0..6271
    const int b = row / 1568, l = row - b * 1568;
    const float* src = (l < 784) ? (memory + ((size_t)b * 1024 + l) * 768)
                                 : (x + ((size_t)b * 784 + (l - 784)) * 768);
    const int t = threadIdx.x, lane = t & 63, wv = t >> 6;
    __shared__ float red[8];

    float v[3];
#pragma unroll
    for (int i = 0; i < 3; ++i) v[i] = src[i * 256 + t];

    float s = v[0] + v[1] + v[2];
    float s2 = v[0] * v[0] + v[1] * v[1] + v[2] * v[2];
#pragma unroll
    for (int off = 1; off < 64; off <<= 1) { s += __shfl_xor(s, off, 64); s2 += __shfl_xor(s2, off, 64); }
    if (lane == 0) { red[wv] = s; red[4 + wv] = s2; }
    __syncthreads();
    s = red[0] + red[1] + red[2] + red[3];
    s2 = red[4] + red[5] + red[6] + red[7];
    float mu = s * (1.0f / 768.0f);
    float var = s2 * (1.0f / 768.0f) - mu * mu;
    float rs = rsqrtf(fmaxf(var, 0.0f) + 1e-5f);

    float w[3];
#pragma unroll
    for (int i = 0; i < 3; ++i) {
        int c = i * 256 + t;
        w[i] = (v[i] - mu) * rs * g1[c] + b1[c];
    }
    if (l >= 784) {
        float* xr = xres + ((size_t)b * 784 + (l - 784)) * 768;
#pragma unroll
        for (int i = 0; i < 3; ++i) xr[i * 256 + t] = w[i];
    }

    s = w[0] + w[1] + w[2];
    s2 = w[0] * w[0] + w[1] * w[1] + w[2] * w[2];
#pragma unroll
    for (int off = 1; off < 64; off <<= 1) { s += __shfl_xor(s, off, 64); s2 += __shfl_xor(s2, off, 64); }
    __syncthreads();
    if (lane == 0) { red[wv] = s; red[4 + wv] = s2; }
    __syncthreads();
    s = red[0] + red[1] + red[2] + red[3];
    s2 = red[4] + red[5] + red[6] + red[7];
    float mu2 = s * (1.0f / 768.0f);
    float var2 = s2 * (1.0f / 768.0f) - mu2 * mu2;
    float rs2 = rsqrtf(fmaxf(var2, 0.0f) + 1e-5f);

    bf16* hh_ = hH + (size_t)row * 768;
    bf16* hl_ = hL + (size_t)row * 768;
#pragma unroll
    for (int i = 0; i < 3; ++i) {
        int c = i * 256 + t;
        float hv = (w[i] - mu2) * rs2 * ga[c] + ba[c];
        bf16 hvh = (bf16)hv;
        hh_[c] = hvh;
        hl_[c] = (bf16)(hv - (float)hvh);
    }
}

// ---------------------------------------------------------------------------
// Plane GEMM: C = A*B^T, A/B given as bf16 hi/lo planes (split precomputed).
// 128x128 tile, BK=32, 4 waves x 64x64, 3 MFMA per product (al*bh+ah*bl+ah*bh).
// MODE 0: planes out. 1: fp32 acc+bias. 2: silu planes out. 3: fp32 acc+bias+resid.
// ---------------------------------------------------------------------------
template <int MODE>
__global__ __launch_bounds__(256, 2) void gemm_pl(
    const bf16* __restrict__ Ah, const bf16* __restrict__ Al,
    const bf16* __restrict__ Bh, const bf16* __restrict__ Bl,
    int M, int N, int K,
    const float* __restrict__ bias, const float* __restrict__ resid,
    float* __restrict__ Cf, bf16* __restrict__ Ch, bf16* __restrict__ Cl)
{
    __shared__ __align__(16) bf16 Ahs[128 * 32], Als[128 * 32];
    __shared__ __align__(16) bf16 Bhs[128 * 32], Bls[128 * 32];
    const int t = threadIdx.x, lane = t & 63, wv = t >> 6;
    const int row0 = blockIdx.y * 128, col0 = blockIdx.x * 128;
    const int ro = (wv >> 1) * 64, co = (wv & 1) * 64;

    f32x4 acc[4][4] = {};

    for (int k0 = 0; k0 < K; k0 += 32) {
#pragma unroll
        for (int it = 0; it < 2; ++it) {
            int f = it * 256 + t;
            int r = f >> 2, kc = (f & 3) * 8;
            int ra = row0 + r; if (ra >= M) ra = M - 1;
            size_t oa = (size_t)ra * K + k0 + kc;
            size_t ob = (size_t)(col0 + r) * K + k0 + kc;
            *(bf16x8*)&Ahs[f * 8] = *(const bf16x8*)(Ah + oa);
            *(bf16x8*)&Als[f * 8] = *(const bf16x8*)(Al + oa);
            *(bf16x8*)&Bhs[f * 8] = *(const bf16x8*)(Bh + ob);
            *(bf16x8*)&Bls[f * 8] = *(const bf16x8*)(Bl + ob);
        }
        __syncthreads();
        bf16x8 ah[4], al[4], bh[4], bl[4];
#pragma unroll
        for (int i = 0; i < 4; ++i) {
            int o = (ro + i * 16 + (lane & 15)) * 32 + (lane >> 4) * 8;
            ah[i] = *(const bf16x8*)&Ahs[o];
            al[i] = *(const bf16x8*)&Als[o];
        }
#pragma unroll
        for (int j = 0; j < 4; ++j) {
            int o = (co + j * 16 + (lane & 15)) * 32 + (lane >> 4) * 8;
            bh[j] = *(const bf16x8*)&Bhs[o];
            bl[j] = *(const bf16x8*)&Bls[o];
        }
#pragma unroll
        for (int i = 0; i < 4; ++i)
#pragma unroll
            for (int j = 0; j < 4; ++j) {
                acc[i][j] = __builtin_amdgcn_mfma_f32_16x16x32_bf16(al[i], bh[j], acc[i][j], 0, 0, 0);
                acc[i][j] = __builtin_amdgcn_mfma_f32_16x16x32_bf16(ah[i], bl[j], acc[i][j], 0, 0, 0);
                acc[i][j] = __builtin_amdgcn_mfma_f32_16x16x32_bf16(ah[i], bh[j], acc[i][j], 0, 0, 0);
            }
        __syncthreads();
    }

#pragma unroll
    for (int i = 0; i < 4; ++i)
#pragma unroll
        for (int j = 0; j < 4; ++j)
#pragma unroll
            for (int r = 0; r < 4; ++r) {
                int row = row0 + ro + i * 16 + (lane >> 4) * 4 + r;
                int col = col0 + co + j * 16 + (lane & 15);
                if (row >= M) continue;
                float v = acc[i][j][r];
                size_t idx = (size_t)row * N + col;
                if (MODE == 0) {
                    bf16 hh = (bf16)v;
                    Ch[idx] = hh; Cl[idx] = (bf16)(v - (float)hh);
                } else if (MODE == 1) {
                    Cf[idx] = v + bias[col];
                } else if (MODE == 2) {
                    v += bias[col];
                    v = v / (1.0f + __expf(-v));
                    bf16 hh = (bf16)v;
                    Ch[idx] = hh; Cl[idx] = (bf16)(v - (float)hh);
                } else {
                    Cf[idx] = v + bias[col] + resid[idx];
                }
            }
}

// ---------------------------------------------------------------------------
// Flash attention on planes. Block = (w, qgroup, h, b): grid.x = 16 (w*4+g).
// Each wave owns ONE q-tile (tile = g*4+wv, 13 valid per window).
// Ks XOR-swizzled (8-elem chunks), Vt/Pl padded to 40-elem rows.
// Scale 1/8 applied to logits post-MFMA. Analytic MAC mask (== real mask).
// Output: hi/lo planes for the out-projection GEMM.
// ---------------------------------------------------------------------------
__global__ __launch_bounds__(256) void attn_kernel(
    const bf16* __restrict__ qh_, const bf16* __restrict__ ql_,
    bf16* __restrict__ oh_, bf16* __restrict__ ol_)
{
    const int w = blockIdx.x >> 2, g = blockIdx.x & 3;
    const int hh = blockIdx.y, b = blockIdx.z;
    const int kmax = (5 + w) * 196, nkt = (kmax + 31) / 32;
    const int t = threadIdx.x, lane = t & 63, wv = t >> 6;
    const int tile = g * 4 + wv;                  // 0..15; >12 idle (wave-uniform)
    const int l15 = lane & 15, q8 = lane >> 4;

    __shared__ __align__(16) bf16 Ks_h[32 * 64], Ks_l[32 * 64];
    __shared__ __align__(16) bf16 Vt_h[64 * 40], Vt_l[64 * 40];
    __shared__ __align__(16) bf16 Pl_h[4][16 * 40], Pl_l[4][16 * 40];

    const size_t bbase = (size_t)b * 1568 * 2304;

    int tcl = tile > 12 ? 12 : tile;
    int qr0 = tcl * 16 + l15; if (qr0 > 195) qr0 = 195;
    const size_t qoff = bbase + (size_t)(784 + w * 196 + qr0) * 2304 + hh * 64 + q8 * 8;
    bf16x8 qfh[2], qfl[2];
#pragma unroll
    for (int p = 0; p < 2; ++p) {
        qfh[p] = *(const bf16x8*)(qh_ + qoff + p * 32);
        qfl[p] = *(const bf16x8*)(ql_ + qoff + p * 32);
    }

    float m_i[4], l_i[4];
    f32x4 oacc[4];
#pragma unroll
    for (int r = 0; r < 4; ++r) { m_i[r] = -1e30f; l_i[r] = 0.0f; }
#pragma unroll
    for (int nd = 0; nd < 4; ++nd) oacc[nd] = f32x4{0.f, 0.f, 0.f, 0.f};

    for (int kt = 0; kt < nkt; ++kt) {
        __syncthreads();
        {
            int row = t >> 3, c8 = (t & 7) * 8;
            int cs = c8 ^ ((row & 7) * 8);          // XOR swizzle, 8-elem chunks
            const size_t koff = bbase + (size_t)(kt * 32 + row) * 2304 + 768 + hh * 64 + c8;
            *(bf16x8*)&Ks_h[row * 64 + cs] = *(const bf16x8*)(qh_ + koff);
            *(bf16x8*)&Ks_l[row * 64 + cs] = *(const bf16x8*)(ql_ + koff);
            bf16x8 vh8 = *(const bf16x8*)(qh_ + koff + 768);
            bf16x8 vl8 = *(const bf16x8*)(ql_ + koff + 768);
#pragma unroll
            for (int j = 0; j < 8; ++j) {
                Vt_h[(c8 + j) * 40 + row] = vh8[j];
                Vt_l[(c8 + j) * 40 + row] = vl8[j];
            }
        }
        __syncthreads();

        bf16x8 kfh[2][2], kfl[2][2], vth[4], vtl[4];
#pragma unroll
        for (int nb = 0; nb < 2; ++nb)
#pragma unroll
            for (int p = 0; p < 2; ++p) {
                int row = nb * 16 + l15;
                int c = (p * 32 + q8 * 8) ^ ((row & 7) * 8);
                kfh[nb][p] = *(const bf16x8*)&Ks_h[row * 64 + c];
                kfl[nb][p] = *(const bf16x8*)&Ks_l[row * 64 + c];
            }
#pragma unroll
        for (int nd = 0; nd < 4; ++nd) {
            int o = (nd * 16 + l15) * 40 + q8 * 8;
            vth[nd] = *(const bf16x8*)&Vt_h[o];
            vtl[nd] = *(const bf16x8*)&Vt_l[o];
        }

        if (tile <= 12) {
            f32x4 s0 = {0.f, 0.f, 0.f, 0.f}, s1 = {0.f, 0.f, 0.f, 0.f};
#pragma unroll
            for (int p = 0; p < 2; ++p) {
                s0 = __builtin_amdgcn_mfma_f32_16x16x32_bf16(qfl[p], kfh[0][p], s0, 0, 0, 0);
                s0 = __builtin_amdgcn_mfma_f32_16x16x32_bf16(qfh[p], kfl[0][p], s0, 0, 0, 0);
                s0 = __builtin_amdgcn_mfma_f32_16x16x32_bf16(qfh[p], kfh[0][p], s0, 0, 0, 0);
                s1 = __builtin_amdgcn_mfma_f32_16x16x32_bf16(qfl[p], kfh[1][p], s1, 0, 0, 0);
                s1 = __builtin_amdgcn_mfma_f32_16x16x32_bf16(qfh[p], kfl[1][p], s1, 0, 0, 0);
                s1 = __builtin_amdgcn_mfma_f32_16x16x32_bf16(qfh[p], kfh[1][p], s1, 0, 0, 0);
            }
            s0 = s0 * 0.125f;
            s1 = s1 * 0.125f;
            const float NEG = -1e30f;
            int key0 = kt * 32 + l15;
            if (key0 >= kmax)      { s0[0] = s0[1] = s0[2] = s0[3] = NEG; }
            if (key0 + 16 >= kmax) { s1[0] = s1[1] = s1[2] = s1[3] = NEG; }
#pragma unroll
            for (int r = 0; r < 4; ++r) {
                float mx = fmaxf(s0[r], s1[r]);
#pragma unroll
                for (int off = 1; off < 16; off <<= 1) mx = fmaxf(mx, __shfl_xor(mx, off, 64));
                float mnew = fmaxf(m_i[r], mx);
                float alpha = __expf(m_i[r] - mnew);
                float p0 = (s0[r] < -1e29f) ? 0.0f : __expf(s0[r] - mnew);
                float p1 = (s1[r] < -1e29f) ? 0.0f : __expf(s1[r] - mnew);
                float sum = p0 + p1;
#pragma unroll
                for (int off = 1; off < 16; off <<= 1) sum += __shfl_xor(sum, off, 64);
                l_i[r] = l_i[r] * alpha + sum;
                m_i[r] = mnew;
#pragma unroll
                for (int nd = 0; nd < 4; ++nd) oacc[nd][r] *= alpha;
                int pr = q8 * 4 + r;
                bf16 p0h = (bf16)p0, p1h = (bf16)p1;
                Pl_h[wv][pr * 40 + l15] = p0h;       Pl_l[wv][pr * 40 + l15] = (bf16)(p0 - (float)p0h);
                Pl_h[wv][pr * 40 + 16 + l15] = p1h;  Pl_l[wv][pr * 40 + 16 + l15] = (bf16)(p1 - (float)p1h);
            }
            asm volatile("s_waitcnt lgkmcnt(0)" ::: "memory");   // wave-private Pl RAW
            bf16x8 pfh = *(const bf16x8*)&Pl_h[wv][l15 * 40 + q8 * 8];
            bf16x8 pfl = *(const bf16x8*)&Pl_l[wv][l15 * 40 + q8 * 8];
#pragma unroll
            for (int nd = 0; nd < 4; ++nd) {
                oacc[nd] = __builtin_amdgcn_mfma_f32_16x16x32_bf16(pfl, vth[nd], oacc[nd], 0, 0, 0);
                oacc[nd] = __builtin_amdgcn_mfma_f32_16x16x32_bf16(pfh, vtl[nd], oacc[nd], 0, 0, 0);
                oacc[nd] = __builtin_amdgcn_mfma_f32_16x16x32_bf16(pfh, vth[nd], oacc[nd], 0, 0, 0);
            }
        }
    }

    if (tile <= 12) {
#pragma unroll
        for (int r = 0; r < 4; ++r) {
            int qr = tile * 16 + q8 * 4 + r;
            if (qr >= 196) continue;
            float inv = 1.0f / l_i[r];
            size_t row = (size_t)b * 784 + w * 196 + qr;
#pragma unroll
            for (int nd = 0; nd < 4; ++nd) {
                float ov = oacc[nd][r] * inv;
                bf16 oh = (bf16)ov;
                size_t idx = row * 768 + hh * 64 + nd * 16 + l15;
                oh_[idx] = oh;
                ol_[idx] = (bf16)(ov - (float)oh);
            }
        }
    }
}

// ---------------------------------------------------------------------------
// y = xres + att (fp32), y2 = LN2(y) as hi/lo planes. Block per x-row (3136).
// ---------------------------------------------------------------------------
__global__ __launch_bounds__(256) void ln2_resid(
    const float* __restrict__ xres, const float* __restrict__ att,
    const float* __restrict__ g2, const float* __restrict__ b2,
    float* __restrict__ y, bf16* __restrict__ y2H, bf16* __restrict__ y2L)
{
    const int row = blockIdx.x;
    const float* xr = xres + (size_t)row * 768;
    const float* ar = att + (size_t)row * 768;
    const int t = threadIdx.x, lane = t & 63, wv = t >> 6;
    __shared__ float red[8];

    float v[3];
    float* yr = y + (size_t)row * 768;
#pragma unroll
    for (int i = 0; i < 3; ++i) {
        int c = i * 256 + t;
        v[i] = xr[c] + ar[c];
        yr[c] = v[i];
    }
    float s = v[0] + v[1] + v[2];
    float s2 = v[0] * v[0] + v[1] * v[1] + v[2] * v[2];
#pragma unroll
    for (int off = 1; off < 64; off <<= 1) { s += __shfl_xor(s, off, 64); s2 += __shfl_xor(s2, off, 64); }
    if (lane == 0) { red[wv] = s; red[4 + wv] = s2; }
    __syncthreads();
    s = red[0] + red[1] + red[2] + red[3];
    s2 = red[4] + red[5] + red[6] + red[7];
    float mu = s * (1.0f / 768.0f);
    float var = s2 * (1.0f / 768.0f) - mu * mu;
    float rs = rsqrtf(fmaxf(var, 0.0f) + 1e-5f);

    bf16* yh = y2H + (size_t)row * 768;
    bf16* yl = y2L + (size_t)row * 768;
#pragma unroll
    for (int i = 0; i < 3; ++i) {
        int c = i * 256 + t;
        float yv = (v[i] - mu) * rs * g2[c] + b2[c];
        bf16 yvh = (bf16)yv;
        yh[c] = yvh;
        yl[c] = (bf16)(yv - (float)yvh);
    }
}

// ---------------------------------------------------------------------------
extern "C" void kernel_launch(void* const* d_in, const int* in_sizes, int n_in,
                              void* d_out, int out_size, void* d_ws, size_t ws_size,
                              hipStream_t stream)
{
    (void)in_sizes; (void)n_in; (void)out_size; (void)ws_size;
    const float* x        = (const float*)d_in[0];
    const float* memory   = (const float*)d_in[1];
    const float* ln_att_g = (const float*)d_in[2];
    const float* ln_att_b = (const float*)d_in[3];
    const float* w_qkv    = (const float*)d_in[4];
    const float* w_out    = (const float*)d_in[5];
    const float* b_out    = (const float*)d_in[6];
    const float* ln1_g    = (const float*)d_in[7];
    const float* ln1_b    = (const float*)d_in[8];
    const float* ln2_g    = (const float*)d_in[9];
    const float* ln2_b    = (const float*)d_in[10];
    const float* w1       = (const float*)d_in[11];
    const float* b1       = (const float*)d_in[12];
    const float* w2       = (const float*)d_in[13];
    const float* b2       = (const float*)d_in[14];

    // ---- workspace layout (total 115,015,680 B ≈ 109.7 MiB) ----
    char* ws = (char*)d_ws;
    const size_t SZF  = (size_t)3136 * 768 * 4;     // 9,633,792  fp32 x-rows
    const size_t SZP  = (size_t)3136 * 768 * 2;     // 4,816,896  bf16 plane x-rows
    const size_t SZHP = (size_t)6272 * 768 * 2;     // 9,633,792  bf16 plane all rows
    const size_t SZQP = (size_t)6272 * 2304 * 2;    // 28,901,376 bf16 plane qkv
    const size_t SZFP = (size_t)3136 * 3072 * 2;    // 19,267,584 bf16 plane ff

    float* xres = (float*)(ws);                                   // [0, SZF)
    bf16* hH  = (bf16*)(ws + SZF);                                // h planes (dead after QKV)
    bf16* hL  = (bf16*)(ws + SZF + SZHP);
    bf16* aoH = (bf16*)(ws + SZF);                                // reuse hH region
    bf16* aoL = (bf16*)(ws + SZF + SZP);
    float* att = (float*)(ws + SZF + 2 * SZP);                    // reuse hL region (2*SZP==SZHP)
    bf16* y2H = (bf16*)(ws + SZF);                                // reuse ao region after out-proj
    bf16* y2L = (bf16*)(ws + SZF + SZP);
    const size_t OQ = SZF + 2 * SZHP;                             // 28,901,376
    bf16* qkvH = (bf16*)(ws + OQ);
    bf16* qkvL = (bf16*)(ws + OQ + SZQP);
    float* y   = (float*)(ws + OQ);                               // reuse qkv after attention
    bf16* ffH  = (bf16*)(ws + OQ + SZF);
    bf16* ffL  = (bf16*)(ws + OQ + SZF + SZFP);
    const size_t OW = OQ + 2 * SZQP;                              // 86,704,128
    bf16* wqH = (bf16*)(ws + OW);
    bf16* wqL = (bf16*)(ws + OW + 3538944);
    bf16* woH = (bf16*)(ws + OW + 2 * 3538944);
    bf16* woL = (bf16*)(ws + OW + 2 * 3538944 + 1179648);
    bf16* w1H = (bf16*)(ws + OW + 2 * 3538944 + 2 * 1179648);
    bf16* w1L = (bf16*)(ws + OW + 2 * 3538944 + 2 * 1179648 + 4718592);
    bf16* w2H = (bf16*)(ws + OW + 2 * 3538944 + 2 * 1179648 + 2 * 4718592);
    bf16* w2L = (bf16*)(ws + OW + 2 * 3538944 + 2 * 1179648 + 3 * 4718592);

    // 0) pre-split weights into hi/lo planes (once per launch)
    split_planes<<<512, 256, 0, stream>>>(w_qkv, wqH, wqL, 1769472);
    split_planes<<<512, 256, 0, stream>>>(w_out, woH, woL, 589824);
    split_planes<<<512, 256, 0, stream>>>(w1,    w1H, w1L, 2359296);
    split_planes<<<512, 256, 0, stream>>>(w2,    w2H, w2L, 2359296);

    // 1) LN1 + LN_att -> xres fp32, h planes
    prep_ln<<<6272, 256, 0, stream>>>(x, memory, ln1_g, ln1_b, ln_att_g, ln_att_b, xres, hH, hL);

    // 2) qkv planes = h @ w_qkv^T  (M=6272, N=2304, K=768)
    gemm_pl<0><<<dim3(18, 49), 256, 0, stream>>>(hH, hL, wqH, wqL, 6272, 2304, 768,
                                                 nullptr, nullptr, nullptr, qkvH, qkvL);

    // 3) attention -> ao planes   (grid: 16 = w*4+qgroup)
    attn_kernel<<<dim3(16, 12, 4), 256, 0, stream>>>(qkvH, qkvL, aoH, aoL);

    // 4) att = ao @ w_out^T + b_out  (M=3136, N=768, K=768) -> fp32
    gemm_pl<1><<<dim3(6, 25), 256, 0, stream>>>(aoH, aoL, woH, woL, 3136, 768, 768,
                                                b_out, nullptr, att, nullptr, nullptr);

    // 5) y = xres + att ; y2 planes = LN2(y)
    ln2_resid<<<3136, 256, 0, stream>>>(xres, att, ln2_g, ln2_b, y, y2H, y2L);

    // 6) ff planes = silu(y2 @ w1^T + b1)  (M=3136, N=3072, K=768)
    gemm_pl<2><<<dim3(24, 25), 256, 0, stream>>>(y2H, y2L, w1H, w1L, 3136, 3072, 768,
                                                 b1, nullptr, nullptr, ffH, ffL);

    // 7) out = y + ff @ w2^T + b2  (M=3136, N=768, K=3072) -> fp32 d_out
    gemm_pl<3><<<dim3(6, 25), 256, 0, stream>>>(ffH, ffL, w2H, w2L, 3136, 768, 3072,
                                                b2, y, (float*)d_out, nullptr, nullptr);
}

// Round 11
// 609.303 us; speedup vs baseline: 1.3161x; 1.0969x over previous
//
#include <hip/hip_runtime.h>
#include <cstdint>

typedef __bf16 bf16;
typedef __bf16 bf16x8 __attribute__((ext_vector_type(8)));
typedef float f32x4 __attribute__((ext_vector_type(4)));

#define AS1 __attribute__((address_space(1)))
#define AS3 __attribute__((address_space(3)))

// Async global->LDS, 16B per lane. LDS dest must be wave-uniform base;
// HW writes lane i at base + i*16 (m97/m104 semantics).
__device__ __forceinline__ void load16_lds(const void* gp, void* lds_base_wave_uniform) {
    __builtin_amdgcn_global_load_lds((AS1 void*)((void*)gp),
                                     (AS3 void*)lds_base_wave_uniform, 16, 0, 0);
}

// ---------------------------------------------------------------------------
// fp32 -> (hi, lo) bf16 planes.
// ---------------------------------------------------------------------------
__global__ __launch_bounds__(256) void split_planes(const float* __restrict__ src,
                                                    bf16* __restrict__ h,
                                                    bf16* __restrict__ l, int n)
{
    const int stride = gridDim.x * blockDim.x;
    for (int i = blockIdx.x * blockDim.x + threadIdx.x; i < n; i += stride) {
        float v = src[i];
        bf16 hh = (bf16)v;
        h[i] = hh;
        l[i] = (bf16)(v - (float)hh);
    }
}

// ---------------------------------------------------------------------------
// LN1 -> xres (fp32, x rows only); LN_att(LN1) -> h hi/lo planes (all rows).
// ---------------------------------------------------------------------------
__global__ __launch_bounds__(256) void prep_ln(
    const float* __restrict__ x, const float* __restrict__ memory,
    const float* __restrict__ g1, const float* __restrict__ b1,
    const float* __restrict__ ga, const float* __restrict__ ba,
    float* __restrict__ xres, bf16* __restrict__ hH, bf16* __restrict__ hL)
{
    const int row = blockIdx.x;            // 0..6271
    const int b = row / 1568, l = row - b * 1568;
    const float* src = (l < 784) ? (memory + ((size_t)b * 1024 + l) * 768)
                                 : (x + ((size_t)b * 784 + (l - 784)) * 768);
    const int t = threadIdx.x, lane = t & 63, wv = t >> 6;
    __shared__ float red[8];

    float v[3];
#pragma unroll
    for (int i = 0; i < 3; ++i) v[i] = src[i * 256 + t];

    float s = v[0] + v[1] + v[2];
    float s2 = v[0] * v[0] + v[1] * v[1] + v[2] * v[2];
#pragma unroll
    for (int off = 1; off < 64; off <<= 1) { s += __shfl_xor(s, off, 64); s2 += __shfl_xor(s2, off, 64); }
    if (lane == 0) { red[wv] = s; red[4 + wv] = s2; }
    __syncthreads();
    s = red[0] + red[1] + red[2] + red[3];
    s2 = red[4] + red[5] + red[6] + red[7];
    float mu = s * (1.0f / 768.0f);
    float var = s2 * (1.0f / 768.0f) - mu * mu;
    float rs = rsqrtf(fmaxf(var, 0.0f) + 1e-5f);

    float w[3];
#pragma unroll
    for (int i = 0; i < 3; ++i) {
        int c = i * 256 + t;
        w[i] = (v[i] - mu) * rs * g1[c] + b1[c];
    }
    if (l >= 784) {
        float* xr = xres + ((size_t)b * 784 + (l - 784)) * 768;
#pragma unroll
        for (int i = 0; i < 3; ++i) xr[i * 256 + t] = w[i];
    }

    s = w[0] + w[1] + w[2];
    s2 = w[0] * w[0] + w[1] * w[1] + w[2] * w[2];
#pragma unroll
    for (int off = 1; off < 64; off <<= 1) { s += __shfl_xor(s, off, 64); s2 += __shfl_xor(s2, off, 64); }
    __syncthreads();
    if (lane == 0) { red[wv] = s; red[4 + wv] = s2; }
    __syncthreads();
    s = red[0] + red[1] + red[2] + red[3];
    s2 = red[4] + red[5] + red[6] + red[7];
    float mu2 = s * (1.0f / 768.0f);
    float var2 = s2 * (1.0f / 768.0f) - mu2 * mu2;
    float rs2 = rsqrtf(fmaxf(var2, 0.0f) + 1e-5f);

    bf16* hh_ = hH + (size_t)row * 768;
    bf16* hl_ = hL + (size_t)row * 768;
#pragma unroll
    for (int i = 0; i < 3; ++i) {
        int c = i * 256 + t;
        float hv = (w[i] - mu2) * rs2 * ga[c] + ba[c];
        bf16 hvh = (bf16)hv;
        hh_[c] = hvh;
        hl_[c] = (bf16)(hv - (float)hvh);
    }
}

// ---------------------------------------------------------------------------
// Plane GEMM with async global->LDS staging (width 16, m97 pattern).
// C = A*B^T; A/B as bf16 hi/lo planes; 128x128 tile, BK=32, 4 waves x 64x64.
// MODE 0: planes out. 1: fp32 acc+bias. 2: silu planes out. 3: fp32 acc+bias+resid.
// ---------------------------------------------------------------------------
template <int MODE>
__global__ __launch_bounds__(256, 2) void gemm_pl(
    const bf16* __restrict__ Ah, const bf16* __restrict__ Al,
    const bf16* __restrict__ Bh, const bf16* __restrict__ Bl,
    int M, int N, int K,
    const float* __restrict__ bias, const float* __restrict__ resid,
    float* __restrict__ Cf, bf16* __restrict__ Ch, bf16* __restrict__ Cl)
{
    __shared__ __align__(16) bf16 Ahs[128 * 32], Als[128 * 32];
    __shared__ __align__(16) bf16 Bhs[128 * 32], Bls[128 * 32];
    const int t = threadIdx.x, lane = t & 63, wv = t >> 6;
    const int row0 = blockIdx.y * 128, col0 = blockIdx.x * 128;
    const int ro = (wv >> 1) * 64, co = (wv & 1) * 64;

    f32x4 acc[4][4] = {};

    for (int k0 = 0; k0 < K; k0 += 32) {
#pragma unroll
        for (int it = 0; it < 2; ++it) {
            int f = it * 256 + t;
            int r = f >> 2, kc = (f & 3) * 8;
            int ra = row0 + r; if (ra >= M) ra = M - 1;
            size_t oa = (size_t)ra * K + k0 + kc;
            size_t ob = (size_t)(col0 + r) * K + k0 + kc;
            // wave-uniform LDS base (lane offset applied by HW: +lane*16B)
            size_t lb = (size_t)(it * 256 + wv * 64) * 8;
            load16_lds(Ah + oa, Ahs + lb);
            load16_lds(Al + oa, Als + lb);
            load16_lds(Bh + ob, Bhs + lb);
            load16_lds(Bl + ob, Bls + lb);
        }
        asm volatile("s_waitcnt vmcnt(0)" ::: "memory");
        __syncthreads();
        bf16x8 ah[4], al[4], bh[4], bl[4];
#pragma unroll
        for (int i = 0; i < 4; ++i) {
            int o = (ro + i * 16 + (lane & 15)) * 32 + (lane >> 4) * 8;
            ah[i] = *(const bf16x8*)&Ahs[o];
            al[i] = *(const bf16x8*)&Als[o];
        }
#pragma unroll
        for (int j = 0; j < 4; ++j) {
            int o = (co + j * 16 + (lane & 15)) * 32 + (lane >> 4) * 8;
            bh[j] = *(const bf16x8*)&Bhs[o];
            bl[j] = *(const bf16x8*)&Bls[o];
        }
#pragma unroll
        for (int i = 0; i < 4; ++i)
#pragma unroll
            for (int j = 0; j < 4; ++j) {
                acc[i][j] = __builtin_amdgcn_mfma_f32_16x16x32_bf16(al[i], bh[j], acc[i][j], 0, 0, 0);
                acc[i][j] = __builtin_amdgcn_mfma_f32_16x16x32_bf16(ah[i], bl[j], acc[i][j], 0, 0, 0);
                acc[i][j] = __builtin_amdgcn_mfma_f32_16x16x32_bf16(ah[i], bh[j], acc[i][j], 0, 0, 0);
            }
        __syncthreads();
    }

#pragma unroll
    for (int i = 0; i < 4; ++i)
#pragma unroll
        for (int j = 0; j < 4; ++j)
#pragma unroll
            for (int r = 0; r < 4; ++r) {
                int row = row0 + ro + i * 16 + (lane >> 4) * 4 + r;
                int col = col0 + co + j * 16 + (lane & 15);
                if (row >= M) continue;
                float v = acc[i][j][r];
                size_t idx = (size_t)row * N + col;
                if (MODE == 0) {
                    bf16 hh = (bf16)v;
                    Ch[idx] = hh; Cl[idx] = (bf16)(v - (float)hh);
                } else if (MODE == 1) {
                    Cf[idx] = v + bias[col];
                } else if (MODE == 2) {
                    v += bias[col];
                    v = v / (1.0f + __expf(-v));
                    bf16 hh = (bf16)v;
                    Ch[idx] = hh; Cl[idx] = (bf16)(v - (float)hh);
                } else {
                    Cf[idx] = v + bias[col] + resid[idx];
                }
            }
}

// ---------------------------------------------------------------------------
// Flash attention. Grid: x = hh + 12*b (48), y = w*4+g (16) -> the 16 blocks
// sharing one (hh,b)'s K/V have IDs stride 48 == 0 mod 8 -> same XCD L2.
// QK^T: full hi/lo split (3 MFMA). PV: hi-plane only (error ~0.004, in budget).
// Ks XOR-swizzled; Vt/Pl padded rows (40). Analytic MAC mask (== real mask).
// ---------------------------------------------------------------------------
__global__ __launch_bounds__(256) void attn_kernel(
    const bf16* __restrict__ qh_, const bf16* __restrict__ ql_,
    bf16* __restrict__ oh_, bf16* __restrict__ ol_)
{
    const int hh = blockIdx.x % 12, b = blockIdx.x / 12;
    const int w = blockIdx.y >> 2, g = blockIdx.y & 3;
    const int kmax = (5 + w) * 196, nkt = (kmax + 31) / 32;
    const int t = threadIdx.x, lane = t & 63, wv = t >> 6;
    const int tile = g * 4 + wv;                  // 0..15; >12 idle (wave-uniform)
    const int l15 = lane & 15, q8 = lane >> 4;

    __shared__ __align__(16) bf16 Ks_h[32 * 64], Ks_l[32 * 64];
    __shared__ __align__(16) bf16 Vt_h[64 * 40];
    __shared__ __align__(16) bf16 Pl_h[4][16 * 40];

    const size_t bbase = (size_t)b * 1568 * 2304;

    int tcl = tile > 12 ? 12 : tile;
    int qr0 = tcl * 16 + l15; if (qr0 > 195) qr0 = 195;
    const size_t qoff = bbase + (size_t)(784 + w * 196 + qr0) * 2304 + hh * 64 + q8 * 8;
    bf16x8 qfh[2], qfl[2];
#pragma unroll
    for (int p = 0; p < 2; ++p) {
        qfh[p] = *(const bf16x8*)(qh_ + qoff + p * 32);
        qfl[p] = *(const bf16x8*)(ql_ + qoff + p * 32);
    }

    float m_i[4], l_i[4];
    f32x4 oacc[4];
#pragma unroll
    for (int r = 0; r < 4; ++r) { m_i[r] = -1e30f; l_i[r] = 0.0f; }
#pragma unroll
    for (int nd = 0; nd < 4; ++nd) oacc[nd] = f32x4{0.f, 0.f, 0.f, 0.f};

    for (int kt = 0; kt < nkt; ++kt) {
        __syncthreads();
        {
            int row = t >> 3, c8 = (t & 7) * 8;
            int cs = c8 ^ ((row & 7) * 8);          // XOR swizzle, 8-elem chunks
            const size_t koff = bbase + (size_t)(kt * 32 + row) * 2304 + 768 + hh * 64 + c8;
            *(bf16x8*)&Ks_h[row * 64 + cs] = *(const bf16x8*)(qh_ + koff);
            *(bf16x8*)&Ks_l[row * 64 + cs] = *(const bf16x8*)(ql_ + koff);
            bf16x8 vh8 = *(const bf16x8*)(qh_ + koff + 768);
#pragma unroll
            for (int j = 0; j < 8; ++j)
                Vt_h[(c8 + j) * 40 + row] = vh8[j];
        }
        __syncthreads();

        bf16x8 kfh[2][2], kfl[2][2], vth[4];
#pragma unroll
        for (int nb = 0; nb < 2; ++nb)
#pragma unroll
            for (int p = 0; p < 2; ++p) {
                int row = nb * 16 + l15;
                int c = (p * 32 + q8 * 8) ^ ((row & 7) * 8);
                kfh[nb][p] = *(const bf16x8*)&Ks_h[row * 64 + c];
                kfl[nb][p] = *(const bf16x8*)&Ks_l[row * 64 + c];
            }
#pragma unroll
        for (int nd = 0; nd < 4; ++nd)
            vth[nd] = *(const bf16x8*)&Vt_h[(nd * 16 + l15) * 40 + q8 * 8];

        if (tile <= 12) {
            f32x4 s0 = {0.f, 0.f, 0.f, 0.f}, s1 = {0.f, 0.f, 0.f, 0.f};
#pragma unroll
            for (int p = 0; p < 2; ++p) {
                s0 = __builtin_amdgcn_mfma_f32_16x16x32_bf16(qfl[p], kfh[0][p], s0, 0, 0, 0);
                s0 = __builtin_amdgcn_mfma_f32_16x16x32_bf16(qfh[p], kfl[0][p], s0, 0, 0, 0);
                s0 = __builtin_amdgcn_mfma_f32_16x16x32_bf16(qfh[p], kfh[0][p], s0, 0, 0, 0);
                s1 = __builtin_amdgcn_mfma_f32_16x16x32_bf16(qfl[p], kfh[1][p], s1, 0, 0, 0);
                s1 = __builtin_amdgcn_mfma_f32_16x16x32_bf16(qfh[p], kfl[1][p], s1, 0, 0, 0);
                s1 = __builtin_amdgcn_mfma_f32_16x16x32_bf16(qfh[p], kfh[1][p], s1, 0, 0, 0);
            }
            s0 = s0 * 0.125f;
            s1 = s1 * 0.125f;
            const float NEG = -1e30f;
            int key0 = kt * 32 + l15;
            if (key0 >= kmax)      { s0[0] = s0[1] = s0[2] = s0[3] = NEG; }
            if (key0 + 16 >= kmax) { s1[0] = s1[1] = s1[2] = s1[3] = NEG; }
#pragma unroll
            for (int r = 0; r < 4; ++r) {
                float mx = fmaxf(s0[r], s1[r]);
#pragma unroll
                for (int off = 1; off < 16; off <<= 1) mx = fmaxf(mx, __shfl_xor(mx, off, 64));
                float mnew = fmaxf(m_i[r], mx);
                float alpha = __expf(m_i[r] - mnew);
                float p0 = (s0[r] < -1e29f) ? 0.0f : __expf(s0[r] - mnew);
                float p1 = (s1[r] < -1e29f) ? 0.0f : __expf(s1[r] - mnew);
                float sum = p0 + p1;
#pragma unroll
                for (int off = 1; off < 16; off <<= 1) sum += __shfl_xor(sum, off, 64);
                l_i[r] = l_i[r] * alpha + sum;
                m_i[r] = mnew;
#pragma unroll
                for (int nd = 0; nd < 4; ++nd) oacc[nd][r] *= alpha;
                int pr = q8 * 4 + r;
                Pl_h[wv][pr * 40 + l15] = (bf16)p0;
                Pl_h[wv][pr * 40 + 16 + l15] = (bf16)p1;
            }
            asm volatile("s_waitcnt lgkmcnt(0)" ::: "memory");   // wave-private Pl RAW
            bf16x8 pfh = *(const bf16x8*)&Pl_h[wv][l15 * 40 + q8 * 8];
#pragma unroll
            for (int nd = 0; nd < 4; ++nd)
                oacc[nd] = __builtin_amdgcn_mfma_f32_16x16x32_bf16(pfh, vth[nd], oacc[nd], 0, 0, 0);
        }
    }

    if (tile <= 12) {
#pragma unroll
        for (int r = 0; r < 4; ++r) {
            int qr = tile * 16 + q8 * 4 + r;
            if (qr >= 196) continue;
            float inv = 1.0f / l_i[r];
            size_t row = (size_t)b * 784 + w * 196 + qr;
#pragma unroll
            for (int nd = 0; nd < 4; ++nd) {
                float ov = oacc[nd][r] * inv;
                bf16 oh = (bf16)ov;
                size_t idx = row * 768 + hh * 64 + nd * 16 + l15;
                oh_[idx] = oh;
                ol_[idx] = (bf16)(ov - (float)oh);
            }
        }
    }
}

// ---------------------------------------------------------------------------
// y = xres + att (fp32), y2 = LN2(y) as hi/lo planes. Block per x-row (3136).
// ---------------------------------------------------------------------------
__global__ __launch_bounds__(256) void ln2_resid(
    const float* __restrict__ xres, const float* __restrict__ att,
    const float* __restrict__ g2, const float* __restrict__ b2,
    float* __restrict__ y, bf16* __restrict__ y2H, bf16* __restrict__ y2L)
{
    const int row = blockIdx.x;
    const float* xr = xres + (size_t)row * 768;
    const float* ar = att + (size_t)row * 768;
    const int t = threadIdx.x, lane = t & 63, wv = t >> 6;
    __shared__ float red[8];

    float v[3];
    float* yr = y + (size_t)row * 768;
#pragma unroll
    for (int i = 0; i < 3; ++i) {
        int c = i * 256 + t;
        v[i] = xr[c] + ar[c];
        yr[c] = v[i];
    }
    float s = v[0] + v[1] + v[2];
    float s2 = v[0] * v[0] + v[1] * v[1] + v[2] * v[2];
#pragma unroll
    for (int off = 1; off < 64; off <<= 1) { s += __shfl_xor(s, off, 64); s2 += __shfl_xor(s2, off, 64); }
    if (lane == 0) { red[wv] = s; red[4 + wv] = s2; }
    __syncthreads();
    s = red[0] + red[1] + red[2] + red[3];
    s2 = red[4] + red[5] + red[6] + red[7];
    float mu = s * (1.0f / 768.0f);
    float var = s2 * (1.0f / 768.0f) - mu * mu;
    float rs = rsqrtf(fmaxf(var, 0.0f) + 1e-5f);

    bf16* yh = y2H + (size_t)row * 768;
    bf16* yl = y2L + (size_t)row * 768;
#pragma unroll
    for (int i = 0; i < 3; ++i) {
        int c = i * 256 + t;
        float yv = (v[i] - mu) * rs * g2[c] + b2[c];
        bf16 yvh = (bf16)yv;
        yh[c] = yvh;
        yl[c] = (bf16)(yv - (float)yvh);
    }
}

// ---------------------------------------------------------------------------
extern "C" void kernel_launch(void* const* d_in, const int* in_sizes, int n_in,
                              void* d_out, int out_size, void* d_ws, size_t ws_size,
                              hipStream_t stream)
{
    (void)in_sizes; (void)n_in; (void)out_size; (void)ws_size;
    const float* x        = (const float*)d_in[0];
    const float* memory   = (const float*)d_in[1];
    const float* ln_att_g = (const float*)d_in[2];
    const float* ln_att_b = (const float*)d_in[3];
    const float* w_qkv    = (const float*)d_in[4];
    const float* w_out    = (const float*)d_in[5];
    const float* b_out    = (const float*)d_in[6];
    const float* ln1_g    = (const float*)d_in[7];
    const float* ln1_b    = (const float*)d_in[8];
    const float* ln2_g    = (const float*)d_in[9];
    const float* ln2_b    = (const float*)d_in[10];
    const float* w1       = (const float*)d_in[11];
    const float* b1       = (const float*)d_in[12];
    const float* w2       = (const float*)d_in[13];
    const float* b2       = (const float*)d_in[14];

    // ---- workspace layout (same as R10, ~109.7 MiB) ----
    char* ws = (char*)d_ws;
    const size_t SZF  = (size_t)3136 * 768 * 4;
    const size_t SZP  = (size_t)3136 * 768 * 2;
    const size_t SZHP = (size_t)6272 * 768 * 2;
    const size_t SZQP = (size_t)6272 * 2304 * 2;
    const size_t SZFP = (size_t)3136 * 3072 * 2;

    float* xres = (float*)(ws);
    bf16* hH  = (bf16*)(ws + SZF);
    bf16* hL  = (bf16*)(ws + SZF + SZHP);
    bf16* aoH = (bf16*)(ws + SZF);
    bf16* aoL = (bf16*)(ws + SZF + SZP);
    float* att = (float*)(ws + SZF + 2 * SZP);
    bf16* y2H = (bf16*)(ws + SZF);
    bf16* y2L = (bf16*)(ws + SZF + SZP);
    const size_t OQ = SZF + 2 * SZHP;
    bf16* qkvH = (bf16*)(ws + OQ);
    bf16* qkvL = (bf16*)(ws + OQ + SZQP);
    float* y   = (float*)(ws + OQ);
    bf16* ffH  = (bf16*)(ws + OQ + SZF);
    bf16* ffL  = (bf16*)(ws + OQ + SZF + SZFP);
    const size_t OW = OQ + 2 * SZQP;
    bf16* wqH = (bf16*)(ws + OW);
    bf16* wqL = (bf16*)(ws + OW + 3538944);
    bf16* woH = (bf16*)(ws + OW + 2 * 3538944);
    bf16* woL = (bf16*)(ws + OW + 2 * 3538944 + 1179648);
    bf16* w1H = (bf16*)(ws + OW + 2 * 3538944 + 2 * 1179648);
    bf16* w1L = (bf16*)(ws + OW + 2 * 3538944 + 2 * 1179648 + 4718592);
    bf16* w2H = (bf16*)(ws + OW + 2 * 3538944 + 2 * 1179648 + 2 * 4718592);
    bf16* w2L = (bf16*)(ws + OW + 2 * 3538944 + 2 * 1179648 + 3 * 4718592);

    // 0) pre-split weights into hi/lo planes
    split_planes<<<512, 256, 0, stream>>>(w_qkv, wqH, wqL, 1769472);
    split_planes<<<512, 256, 0, stream>>>(w_out, woH, woL, 589824);
    split_planes<<<512, 256, 0, stream>>>(w1,    w1H, w1L, 2359296);
    split_planes<<<512, 256, 0, stream>>>(w2,    w2H, w2L, 2359296);

    // 1) LN1 + LN_att
    prep_ln<<<6272, 256, 0, stream>>>(x, memory, ln1_g, ln1_b, ln_att_g, ln_att_b, xres, hH, hL);

    // 2) qkv planes = h @ w_qkv^T  (M=6272, N=2304, K=768)
    gemm_pl<0><<<dim3(18, 49), 256, 0, stream>>>(hH, hL, wqH, wqL, 6272, 2304, 768,
                                                 nullptr, nullptr, nullptr, qkvH, qkvL);

    // 3) attention  (grid: x = hh+12*b, y = w*4+g  -> XCD-local K/V sharing)
    attn_kernel<<<dim3(48, 16), 256, 0, stream>>>(qkvH, qkvL, aoH, aoL);

    // 4) att = ao @ w_out^T + b_out  (M=3136, N=768, K=768) -> fp32
    gemm_pl<1><<<dim3(6, 25), 256, 0, stream>>>(aoH, aoL, woH, woL, 3136, 768, 768,
                                                b_out, nullptr, att, nullptr, nullptr);

    // 5) y = xres + att ; y2 planes = LN2(y)
    ln2_resid<<<3136, 256, 0, stream>>>(xres, att, ln2_g, ln2_b, y, y2H, y2L);

    // 6) ff planes = silu(y2 @ w1^T + b1)  (M=3136, N=3072, K=768)
    gemm_pl<2><<<dim3(24, 25), 256, 0, stream>>>(y2H, y2L, w1H, w1L, 3136, 3072, 768,
                                                 b1, nullptr, nullptr, ffH, ffL);

    // 7) out = y + ff @ w2^T + b2  (M=3136, N=768, K=3072) -> fp32 d_out
    gemm_pl<3><<<dim3(6, 25), 256, 0, stream>>>(ffH, ffL, w2H, w2L, 3136, 768, 3072,
                                                b2, y, (float*)d_out, nullptr, nullptr);
}